// Round 15
// baseline (79.423 us; speedup 1.0000x reference)
//
#include <hip/hip_runtime.h>

// Problem constants
#define MM 15   // max_peptide_size
#define RR 64   // aa_rep_size
#define PP 34   // pocket positions
#define FF 9    // filter size
#define AA 20   // alphabet size
#define OW 72   // RR + FF - 1
#define SP 84   // s_s row stride (floats), 16B-aligned
#define KS 12   // kernels row stride (floats), 16B-aligned
#define AJ 16   // adj-float row stride (floats), 16B-aligned

// One block per sample, 256 threads = 4 waves.
// NEW this round: per-sample output staged in LDS (s_o) and written to HBM as
// one flat, line-aligned stream (1 KB contiguous per wave-inst) to eliminate
// partial-cacheline RMW traffic from the 288 B row-segment stores.
__global__ __launch_bounds__(256)
void ppc_kernel(const float* __restrict__ pe,      // [B, M, R]
                const int*   __restrict__ idx,     // [B, P]
                const int*   __restrict__ adj,     // [B, P, M]
                const float* __restrict__ kernels, // [A, F]
                float*       __restrict__ out)     // [B, P, OW]
{
    const int b    = blockIdx.x;
    const int t    = threadIdx.x;
    const int lane = t & 63;
    const int w    = t >> 6;

    __shared__ float  s_kern[AA * KS];       // 240 f
    __shared__ float  s_adjf[PP * AJ];       // 544 f (col 15 = 0)
    __shared__ int    s_idx[PP];
    __shared__ float  s_s[PP * SP];          // 2856 f, zero-padded conv rows
    __shared__ float4 s_o4[(PP * OW) / 4];   // 612 f4 = 2448 f (out staging)
    float* s_o = (float*)s_o4;

    const float* peb  = pe  + (size_t)b * (MM * RR);
    const int*   adjb = adj + (size_t)b * (PP * MM);

    // per-lane pe column straight from global (coalesced, L1/L3-hot)
    float pv[MM];
    #pragma unroll
    for (int m = 0; m < MM; ++m) pv[m] = peb[m * RR + lane];

    // ---- staging
    if (t < AA * FF) {
        int a = (unsigned)t / FF, j = t - a * FF;
        s_kern[a * KS + j] = kernels[t];
    }
    for (int i = t; i < PP * MM; i += 256) {
        int p = (unsigned)i / MM, m = i - p * MM;
        s_adjf[p * AJ + m] = (float)adjb[i];
    }
    if (t < PP) {
        s_adjf[t * AJ + 15] = 0.0f;          // kill the unused .w gate
        s_idx[t] = idx[(size_t)b * PP + t];
    }
    if (t < PP * 5) {   // conv zero pads: dwords {0..7} and {72..83} per row
        int p = (unsigned)t / 5, k = t - p * 5;
        int off = p * SP + (k < 2 ? k * 4 : 72 + (k - 2) * 4);
        *(float4*)&s_s[off] = make_float4(0.f, 0.f, 0.f, 0.f);
    }
    __syncthreads();

    // ---- Phase B: wave w owns rows p = w+4j; adj via broadcast b128 reads
    #pragma unroll
    for (int j = 0; j < 9; ++j) {
        const int p = w + 4 * j;              // wave-uniform
        if (p < PP) {
            const float* g = &s_adjf[p * AJ];
            const float4 g0 = *(const float4*)&g[0];
            const float4 g1 = *(const float4*)&g[4];
            const float4 g2 = *(const float4*)&g[8];
            const float4 g3 = *(const float4*)&g[12];   // .w == 0
            float acc;
            acc  = g0.x * pv[0]  + g0.y * pv[1]  + g0.z * pv[2]  + g0.w * pv[3];
            acc += g1.x * pv[4]  + g1.y * pv[5]  + g1.z * pv[6]  + g1.w * pv[7];
            acc += g2.x * pv[8]  + g2.y * pv[9]  + g2.z * pv[10] + g2.w * pv[11];
            acc += g3.x * pv[12] + g3.y * pv[13] + g3.z * pv[14];
            s_s[p * SP + 8 + lane] = acc;
        }
    }
    __syncthreads();

    // ---- Phase C: 3 passes; lane -> (rowk = lane/18, o0 = 4*(lane%18));
    // results go to the LDS out-staging buffer, not global.
    const int rowk = (unsigned)lane / 18u;       // 0..3 (3 = idle)
    const int o0   = (lane - 18 * rowk) << 2;    // 0..68

    #pragma unroll
    for (int k = 0; k < 3; ++k) {
        const int p = w + 12 * k + 4 * rowk;     // this wave's rows
        if (rowk < 3 && p < PP) {
            const float* kb = &s_kern[s_idx[p] * KS];   // group-uniform bcast
            const float4 k0 = *(const float4*)&kb[0];
            const float4 k1 = *(const float4*)&kb[4];
            float kf[FF] = {k0.x,k0.y,k0.z,k0.w, k1.x,k1.y,k1.z,k1.w, kb[8]};

            const float* row = &s_s[p * SP];
            float wv[12];
            *(float4*)&wv[0] = *(const float4*)&row[o0];      // aligned b128
            *(float4*)&wv[4] = *(const float4*)&row[o0 + 4];
            *(float4*)&wv[8] = *(const float4*)&row[o0 + 8];

            float ax=0, ay=0, az=0, aw=0;
            #pragma unroll
            for (int jj = 0; jj < FF; ++jj) {
                const float kk = kf[jj];
                ax += kk * wv[8  - jj];
                ay += kk * wv[9  - jj];
                az += kk * wv[10 - jj];
                aw += kk * wv[11 - jj];
            }
            s_o4[(p * OW + o0) >> 2] = make_float4(ax, ay, az, aw);
        }
    }
    __syncthreads();

    // ---- flat, line-aligned output stream: 612 float4 = 9792 B contiguous
    float4* outb4 = (float4*)(out + (size_t)b * (PP * OW));
    #pragma unroll
    for (int k = 0; k < 3; ++k) {
        const int i = t + k * 256;
        if (i < (PP * OW) / 4)
            outb4[i] = s_o4[i];
    }
}

extern "C" void kernel_launch(void* const* d_in, const int* in_sizes, int n_in,
                              void* d_out, int out_size, void* d_ws, size_t ws_size,
                              hipStream_t stream) {
    const float* pe      = (const float*)d_in[0]; // [B,M,R] f32
    const int*   idx     = (const int*)  d_in[1]; // [B,P]   i32
    const int*   adj     = (const int*)  d_in[2]; // [B,P,M] i32
    const float* kernels = (const float*)d_in[3]; // [A,F]   f32
    float*       out     = (float*)d_out;

    const int B = in_sizes[0] / (MM * RR);
    ppc_kernel<<<B, 256, 0, stream>>>(pe, idx, adj, kernels, out);
}